// Round 4
// baseline (5933.075 us; speedup 1.0000x reference)
//
#include <hip/hip_runtime.h>
#include <hip/hip_bf16.h>

// MPNN: 48 sequential message-passing steps (T=3 x DEG=16), fused-weight GEMM
// per step, then readout GEMM + sum + tiny MLP. All fp32 this round.
//
// Folded weights (precomputed once per launch in prep_kernel):
//   Bstep[146][70]: rows 0..69   = Uw[0:70]           (h term)
//                   rows 70..139 = Vw @ Uw[70:140]    (gathered-neighbor term)
//                   rows 140..145= Ew @ Uw[140:146]   (edge term)
//   btot[70] = Ub + Vb@Uw[70:140] + Eb@Uw[140:146]
//   Rc[70][128] = Rw[0:70] + Rw[70:140]               (cat([h,h]) fold)

#define NNODES 200000
#define HD 70
#define KDIM 146
#define DEG 16

__global__ void prep_kernel(const float* __restrict__ Vw, const float* __restrict__ Vb,
                            const float* __restrict__ Ew, const float* __restrict__ Eb,
                            const float* __restrict__ Uw, const float* __restrict__ Ub,
                            const float* __restrict__ Rw,
                            float* __restrict__ Bstep, float* __restrict__ btot,
                            float* __restrict__ Rc) {
    const int t = threadIdx.x;
    // rows 0..69: copy U1 = Uw[0:70]
    for (int idx = t; idx < 70 * 70; idx += 256) Bstep[idx] = Uw[idx];
    // rows 70..139: W2 = Vw @ Uw[70:140]
    for (int idx = t; idx < 70 * 70; idx += 256) {
        const int c = idx / 70, n = idx % 70;
        float s = 0.f;
        for (int c2 = 0; c2 < 70; ++c2) s += Vw[c * 70 + c2] * Uw[(70 + c2) * 70 + n];
        Bstep[(70 + c) * 70 + n] = s;
    }
    // rows 140..145: We = Ew @ Uw[140:146]
    for (int idx = t; idx < 6 * 70; idx += 256) {
        const int c = idx / 70, n = idx % 70;
        float s = 0.f;
        for (int c2 = 0; c2 < 6; ++c2) s += Ew[c * 6 + c2] * Uw[(140 + c2) * 70 + n];
        Bstep[(140 + c) * 70 + n] = s;
    }
    // fused bias
    for (int n = t; n < 70; n += 256) {
        float s = Ub[n];
        for (int c2 = 0; c2 < 70; ++c2) s += Vb[c2] * Uw[(70 + c2) * 70 + n];
        for (int c2 = 0; c2 < 6; ++c2) s += Eb[c2] * Uw[(140 + c2) * 70 + n];
        btot[n] = s;
    }
    // readout fold
    for (int idx = t; idx < 70 * 128; idx += 256) {
        const int c = idx / 128, n = idx % 128;
        Rc[idx] = Rw[c * 128 + n] + Rw[(70 + c) * 128 + n];
    }
}

// One message-passing step for 64 nodes per block.
// C[64][70] = relu( A[64][146] @ B[146][70] + btot ), where A = [hv | hg | e].
// A staged in two phases through one LDS buffer (static LDS <= 64KB).
__global__ __launch_bounds__(256) void step_kernel(
    const float* __restrict__ h_in, const float* __restrict__ edge,
    const int* __restrict__ nbr, const float* __restrict__ Bg,
    const float* __restrict__ btot, float* __restrict__ h_out, const int j) {
    __shared__ __align__(16) float As[76][68];   // phase1: hv[c][m]; phase2: hg[c][m], e rows 70..75
    __shared__ float Bs[KDIM][70];
    __shared__ float bias_s[70];
    __shared__ int gidx[64];
    const int tid = threadIdx.x;
    const int node0 = blockIdx.x * 64;

    if (tid < 64) gidx[tid] = nbr[(node0 + tid) * DEG + j];
    if (tid < 70) bias_s[tid] = btot[tid];
    for (int idx = tid; idx < KDIM * 70; idx += 256)
        Bs[idx / 70][idx % 70] = Bg[idx];
    // hv: contiguous read of 64*70 floats, store transposed
    for (int idx = tid; idx < 64 * 70; idx += 256)
        As[idx % 70][idx / 70] = h_in[node0 * 70 + idx];
    __syncthreads();

    const int tm = tid & 15;        // m-group 0..15 -> rows m0..m0+3
    const int tn = tid >> 4;        // n-group; active if < 14 -> cols n0..n0+4
    const int m0 = tm * 4;
    const int n0 = tn * 5;
    float acc[4][5] = {};

    if (tn < 14) {
        for (int k = 0; k < 70; ++k) {
            const float4 a = *(const float4*)&As[k][m0];
            const float* bp = &Bs[k][n0];
#pragma unroll
            for (int n = 0; n < 5; ++n) {
                const float b = bp[n];
                acc[0][n] += a.x * b; acc[1][n] += a.y * b;
                acc[2][n] += a.z * b; acc[3][n] += a.w * b;
            }
        }
    }
    __syncthreads();  // done reading phase-1 As

    // phase 2: gathered neighbor rows + edge rows
    for (int idx = tid; idx < 64 * 70; idx += 256) {
        const int m = idx / 70, c = idx % 70;
        As[c][m] = h_in[gidx[m] * 70 + c];
    }
    for (int idx = tid; idx < 64 * 6; idx += 256) {
        const int m = idx / 6, c = idx % 6;
        As[70 + c][m] = edge[((node0 + m) * DEG + j) * 6 + c];
    }
    __syncthreads();

    if (tn < 14) {
        for (int k = 0; k < 76; ++k) {
            const float4 a = *(const float4*)&As[k][m0];
            const float* bp = &Bs[70 + k][n0];
#pragma unroll
            for (int n = 0; n < 5; ++n) {
                const float b = bp[n];
                acc[0][n] += a.x * b; acc[1][n] += a.y * b;
                acc[2][n] += a.z * b; acc[3][n] += a.w * b;
            }
        }
#pragma unroll
        for (int i = 0; i < 4; ++i) {
#pragma unroll
            for (int n = 0; n < 5; ++n) {
                const float v = fmaxf(acc[i][n] + bias_s[n0 + n], 0.f);
                h_out[(node0 + m0 + i) * 70 + n0 + n] = v;
            }
        }
    }
}

// fm[128] += sum over 64 nodes of relu(h @ Rc + Rb)
__global__ __launch_bounds__(256) void readout_kernel(
    const float* __restrict__ h, const float* __restrict__ Rc,
    const float* __restrict__ Rb, float* __restrict__ fm) {
    __shared__ __align__(16) float As[70][68];
    __shared__ float Rs[70][128];
    __shared__ float red[16][132];
    const int tid = threadIdx.x;
    const int node0 = blockIdx.x * 64;

    for (int idx = tid; idx < 70 * 128; idx += 256)
        Rs[idx / 128][idx % 128] = Rc[idx];
    for (int idx = tid; idx < 64 * 70; idx += 256)
        As[idx % 70][idx / 70] = h[node0 * 70 + idx];
    __syncthreads();

    const int tm = tid & 15, tn = tid >> 4;
    const int m0 = tm * 4, n0 = tn * 8;
    float acc[4][8] = {};
    for (int k = 0; k < 70; ++k) {
        const float4 a = *(const float4*)&As[k][m0];
        const float* bp = &Rs[k][n0];
#pragma unroll
        for (int n = 0; n < 8; ++n) {
            const float b = bp[n];
            acc[0][n] += a.x * b; acc[1][n] += a.y * b;
            acc[2][n] += a.z * b; acc[3][n] += a.w * b;
        }
    }
#pragma unroll
    for (int n = 0; n < 8; ++n) {
        const float bias = Rb[n0 + n];
        red[tm][n0 + n] = fmaxf(acc[0][n] + bias, 0.f) + fmaxf(acc[1][n] + bias, 0.f)
                        + fmaxf(acc[2][n] + bias, 0.f) + fmaxf(acc[3][n] + bias, 0.f);
    }
    __syncthreads();
    if (tid < 128) {
        float s = 0.f;
#pragma unroll
        for (int r = 0; r < 16; ++r) s += red[r][tid];
        atomicAdd(&fm[tid], s);
    }
}

__global__ void mlp_kernel(const float* __restrict__ fm,
                           const float* __restrict__ S1w, const float* __restrict__ S1b,
                           const float* __restrict__ S2w, const float* __restrict__ S2b,
                           const float* __restrict__ Hw, const float* __restrict__ Hb,
                           const float* __restrict__ Ow, const float* __restrict__ Ob,
                           float* __restrict__ out) {
    __shared__ float fms[128], a_s[128], b_s[100], c_s[100];
    const int t = threadIdx.x;
    fms[t] = fm[t];
    __syncthreads();
    {
        float s = S1b[t];
        for (int c = 0; c < 128; ++c) s += fms[c] * S1w[c * 128 + t];
        a_s[t] = fmaxf(s, 0.f);
    }
    __syncthreads();
    if (t < 100) {
        float s = S2b[t];
        for (int c = 0; c < 128; ++c) s += a_s[c] * S2w[c * 100 + t];
        b_s[t] = s;  // no activation before hidden layer
    }
    __syncthreads();
    if (t < 100) {
        float s = Hb[t];
        for (int c = 0; c < 100; ++c) s += b_s[c] * Hw[c * 100 + t];
        c_s[t] = fmaxf(s, 0.f);
    }
    __syncthreads();
    if (t == 0) {
        float s = Ob[0];
        for (int c = 0; c < 100; ++c) s += c_s[c] * Ow[c];
        out[0] = s;
    }
}

extern "C" void kernel_launch(void* const* d_in, const int* in_sizes, int n_in,
                              void* d_out, int out_size, void* d_ws, size_t ws_size,
                              hipStream_t stream) {
    const float* h0   = (const float*)d_in[0];
    const float* edge = (const float*)d_in[1];
    const int*   nbr  = (const int*)d_in[2];
    const float* Vw = (const float*)d_in[3];
    const float* Vb = (const float*)d_in[4];
    const float* Ew = (const float*)d_in[5];
    const float* Eb = (const float*)d_in[6];
    const float* Uw = (const float*)d_in[7];
    const float* Ub = (const float*)d_in[8];
    const float* Rw = (const float*)d_in[9];
    const float* Rb = (const float*)d_in[10];
    const float* S1w = (const float*)d_in[11];
    const float* S1b = (const float*)d_in[12];
    const float* S2w = (const float*)d_in[13];
    const float* S2b = (const float*)d_in[14];
    const float* Hw = (const float*)d_in[15];
    const float* Hb = (const float*)d_in[16];
    const float* Ow = (const float*)d_in[17];
    const float* Ob = (const float*)d_in[18];
    float* out = (float*)d_out;

    // workspace layout (needs ~112.1 MB)
    char* ws = (char*)d_ws;
    float* hA    = (float*)(ws);                 // 200000*70 floats = 56 MB
    float* hB    = (float*)(ws + 56000000);      // 56 MB
    float* Bstep = (float*)(ws + 112000000);     // 146*70 = 10220 floats
    float* btot  = Bstep + 10220;                // 70 (+2 pad)
    float* Rc    = btot + 72;                    // 70*128 = 8960 floats
    float* fm    = Rc + 8960;                    // 128 floats

    prep_kernel<<<1, 256, 0, stream>>>(Vw, Vb, Ew, Eb, Uw, Ub, Rw, Bstep, btot, Rc);
    hipMemsetAsync(fm, 0, 128 * sizeof(float), stream);

    const int nblk = NNODES / 64;  // 3125, exact
    const float* cur = h0;
    for (int s = 0; s < 48; ++s) {
        float* o = (s & 1) ? hB : hA;
        step_kernel<<<nblk, 256, 0, stream>>>(cur, edge, nbr, Bstep, btot, o, s & 15);
        cur = o;
    }
    readout_kernel<<<nblk, 256, 0, stream>>>(cur, Rc, Rb, fm);
    mlp_kernel<<<1, 128, 0, stream>>>(fm, S1w, S1b, S2w, S2b, Hw, Hb, Ow, Ob, out);
}

// Round 5
// 3465.022 us; speedup vs baseline: 1.7123x; 1.7123x over previous
//
#include <hip/hip_runtime.h>
#include <hip/hip_bf16.h>

// MPNN: 48 sequential message-passing steps (T=3 x DEG=16).
// This round: step GEMM moved to MFMA bf16 (fp32 accum), h kept fp32 in global.
//   A[64][160] = [hv(70) | hg(70) | e(6) | 0-pad] staged bf16 in LDS, stride 168
//   Bt[80][160] = folded weights, bf16, pre-transposed (n-major) in prep
//   C = relu(A @ B + bias) written fp32.
// Folded weights (prep_kernel):
//   Bstep[146][70]: [Uw[0:70]; Vw@Uw[70:140]; Ew@Uw[140:146]]
//   btot[70] = Ub + Vb@Uw[70:140] + Eb@Uw[140:146]
//   Rc[70][128] = Rw[0:70] + Rw[70:140]   (cat([h,h]) fold)

#define NNODES 200000
#define DEG 16

typedef __attribute__((ext_vector_type(8))) short short8;
typedef __attribute__((ext_vector_type(4))) float f32x4;

__device__ __forceinline__ unsigned short f2bf(float f) {
    unsigned u = __float_as_uint(f);
    unsigned r = 0x7FFFu + ((u >> 16) & 1u);
    return (unsigned short)((u + r) >> 16);
}

__global__ void prep_kernel(const float* __restrict__ Vw, const float* __restrict__ Vb,
                            const float* __restrict__ Ew, const float* __restrict__ Eb,
                            const float* __restrict__ Uw, const float* __restrict__ Ub,
                            const float* __restrict__ Rw,
                            float* __restrict__ Bstep, float* __restrict__ btot,
                            float* __restrict__ Rc,
                            unsigned short* __restrict__ Btg, float* __restrict__ bias80) {
    const int t = threadIdx.x;
    // rows 0..69: U1 = Uw[0:70]
    for (int idx = t; idx < 70 * 70; idx += 256) Bstep[idx] = Uw[idx];
    // rows 70..139: W2 = Vw @ Uw[70:140]
    for (int idx = t; idx < 70 * 70; idx += 256) {
        const int c = idx / 70, n = idx % 70;
        float s = 0.f;
        for (int c2 = 0; c2 < 70; ++c2) s += Vw[c * 70 + c2] * Uw[(70 + c2) * 70 + n];
        Bstep[(70 + c) * 70 + n] = s;
    }
    // rows 140..145: We = Ew @ Uw[140:146]
    for (int idx = t; idx < 6 * 70; idx += 256) {
        const int c = idx / 70, n = idx % 70;
        float s = 0.f;
        for (int c2 = 0; c2 < 6; ++c2) s += Ew[c * 6 + c2] * Uw[(140 + c2) * 70 + n];
        Bstep[(140 + c) * 70 + n] = s;
    }
    // fused bias
    for (int n = t; n < 70; n += 256) {
        float s = Ub[n];
        for (int c2 = 0; c2 < 70; ++c2) s += Vb[c2] * Uw[(70 + c2) * 70 + n];
        for (int c2 = 0; c2 < 6; ++c2) s += Eb[c2] * Uw[(140 + c2) * 70 + n];
        btot[n] = s;
    }
    // readout fold
    for (int idx = t; idx < 70 * 128; idx += 256) {
        const int c = idx / 128, n = idx % 128;
        Rc[idx] = Rw[c * 128 + n] + Rw[(70 + c) * 128 + n];
    }
    __syncthreads();
    // bf16 transposed padded weights: Btg[n][k], n<80, k<160 (zeros in pads)
    for (int idx = t; idx < 80 * 160; idx += 256) {
        const int n = idx / 160, k = idx % 160;
        const float v = (n < 70 && k < 146) ? Bstep[k * 70 + n] : 0.f;
        Btg[idx] = f2bf(v);
    }
    for (int n = t; n < 80; n += 256) bias80[n] = (n < 70) ? btot[n] : 0.f;
}

// One message-passing step, 64 nodes/block, MFMA 16x16x32 bf16.
__global__ __launch_bounds__(256, 3) void step_kernel(
    const float* __restrict__ h_in, const float* __restrict__ edge,
    const int* __restrict__ nbr, const unsigned short* __restrict__ Btg,
    const float* __restrict__ bias80, float* __restrict__ h_out, const int j) {
    __shared__ __align__(16) unsigned short Asb[64][168];  // 21504 B
    __shared__ __align__(16) unsigned short Btb[80][168];  // 26880 B
    __shared__ float bias_s[80];                           // 320 B  -> 48.7 KB: 3 blk/CU
    const int tid = threadIdx.x;
    const int node0 = blockIdx.x * 64;

    for (int i = tid; i < 80; i += 256) bias_s[i] = bias80[i];
    // zero A pad cols [146,160) (B pad rows are zero too; avoids stale-NaN x 0)
    for (int i = tid; i < 64 * 7; i += 256) {
        const int m = i / 7, c = i % 7;
        *(unsigned int*)&Asb[m][146 + 2 * c] = 0u;
    }
    // B tile: coalesced uint copy (80x160 bf16 = 6400 uints)
    {
        const unsigned int* Bg32 = (const unsigned int*)Btg;
        for (int i = tid; i < 80 * 80; i += 256) {
            const int n = i / 80, kp = i % 80;
            ((unsigned int*)&Asb[0][0], (void)0);  // no-op, keep compiler honest
            ((unsigned int*)&Btb[n][0])[kp] = Bg32[i];
        }
    }
    // hv: own-node h rows -> cols [0,70)
    for (int i = tid; i < 64 * 35; i += 256) {
        const int m = i / 35, kp = i % 35;
        const float* p = &h_in[(long)(node0 + m) * 70 + 2 * kp];
        const unsigned int v = (unsigned)f2bf(p[0]) | ((unsigned)f2bf(p[1]) << 16);
        ((unsigned int*)&Asb[m][0])[kp] = v;
    }
    // hg: gathered neighbor rows -> cols [70,140)
    for (int i = tid; i < 64 * 35; i += 256) {
        const int m = i / 35, kp = i % 35;
        const int g = nbr[(node0 + m) * DEG + j];
        const float* p = &h_in[(long)g * 70 + 2 * kp];
        const unsigned int v = (unsigned)f2bf(p[0]) | ((unsigned)f2bf(p[1]) << 16);
        ((unsigned int*)&Asb[m][0])[35 + kp] = v;
    }
    // e: edge feats slot j -> cols [140,146)
    for (int i = tid; i < 64 * 3; i += 256) {
        const int m = i / 3, cp = i % 3;
        const float* p = &edge[((long)(node0 + m) * DEG + j) * 6 + 2 * cp];
        const unsigned int v = (unsigned)f2bf(p[0]) | ((unsigned)f2bf(p[1]) << 16);
        ((unsigned int*)&Asb[m][0])[70 + cp] = v;
    }
    __syncthreads();

    // wave w owns node rows [w*16, w*16+16); 5 N-tiles x 5 K-tiles
    const int w = tid >> 6;
    const int l = tid & 63;
    const int lm = l & 15;           // A row / B col / D col
    const int lhi = l >> 4;          // 0..3
    const int lk = lhi * 8;          // k offset within 32-wide K tile

    short8 bfr[5][5];
#pragma unroll
    for (int kt = 0; kt < 5; ++kt)
#pragma unroll
        for (int nt = 0; nt < 5; ++nt)
            bfr[kt][nt] = *(const short8*)&Btb[nt * 16 + lm][kt * 32 + lk];

    f32x4 acc[5] = {{0.f, 0.f, 0.f, 0.f}, {0.f, 0.f, 0.f, 0.f}, {0.f, 0.f, 0.f, 0.f},
                    {0.f, 0.f, 0.f, 0.f}, {0.f, 0.f, 0.f, 0.f}};
#pragma unroll
    for (int kt = 0; kt < 5; ++kt) {
        const short8 a = *(const short8*)&Asb[w * 16 + lm][kt * 32 + lk];
#pragma unroll
        for (int nt = 0; nt < 5; ++nt)
            acc[nt] = __builtin_amdgcn_mfma_f32_16x16x32_bf16(a, bfr[kt][nt], acc[nt], 0, 0, 0);
    }

    // D: col = lane&15, row = (lane>>4)*4 + reg  (verified layout)
#pragma unroll
    for (int nt = 0; nt < 5; ++nt) {
        const int col = nt * 16 + lm;
        if (col < 70) {
            const float bias = bias_s[col];
#pragma unroll
            for (int r = 0; r < 4; ++r) {
                const int node = node0 + w * 16 + lhi * 4 + r;
                h_out[(long)node * 70 + col] = fmaxf(acc[nt][r] + bias, 0.f);
            }
        }
    }
}

// fm[128] += sum over 64 nodes of relu(h @ Rc + Rb)  (fp32, unchanged)
__global__ __launch_bounds__(256) void readout_kernel(
    const float* __restrict__ h, const float* __restrict__ Rc,
    const float* __restrict__ Rb, float* __restrict__ fm) {
    __shared__ __align__(16) float As[70][68];
    __shared__ float Rs[70][128];
    __shared__ float red[16][132];
    const int tid = threadIdx.x;
    const int node0 = blockIdx.x * 64;

    for (int idx = tid; idx < 70 * 128; idx += 256)
        Rs[idx / 128][idx % 128] = Rc[idx];
    for (int idx = tid; idx < 64 * 70; idx += 256)
        As[idx % 70][idx / 70] = h[node0 * 70 + idx];
    __syncthreads();

    const int tm = tid & 15, tn = tid >> 4;
    const int m0 = tm * 4, n0 = tn * 8;
    float acc[4][8] = {};
    for (int k = 0; k < 70; ++k) {
        const float4 a = *(const float4*)&As[k][m0];
        const float* bp = &Rs[k][n0];
#pragma unroll
        for (int n = 0; n < 8; ++n) {
            const float b = bp[n];
            acc[0][n] += a.x * b; acc[1][n] += a.y * b;
            acc[2][n] += a.z * b; acc[3][n] += a.w * b;
        }
    }
#pragma unroll
    for (int n = 0; n < 8; ++n) {
        const float bias = Rb[n0 + n];
        red[tm][n0 + n] = fmaxf(acc[0][n] + bias, 0.f) + fmaxf(acc[1][n] + bias, 0.f)
                        + fmaxf(acc[2][n] + bias, 0.f) + fmaxf(acc[3][n] + bias, 0.f);
    }
    __syncthreads();
    if (tid < 128) {
        float s = 0.f;
#pragma unroll
        for (int r = 0; r < 16; ++r) s += red[r][tid];
        atomicAdd(&fm[tid], s);
    }
}

__global__ void mlp_kernel(const float* __restrict__ fm,
                           const float* __restrict__ S1w, const float* __restrict__ S1b,
                           const float* __restrict__ S2w, const float* __restrict__ S2b,
                           const float* __restrict__ Hw, const float* __restrict__ Hb,
                           const float* __restrict__ Ow, const float* __restrict__ Ob,
                           float* __restrict__ out) {
    __shared__ float fms[128], a_s[128], b_s[100], c_s[100];
    const int t = threadIdx.x;
    fms[t] = fm[t];
    __syncthreads();
    {
        float s = S1b[t];
        for (int c = 0; c < 128; ++c) s += fms[c] * S1w[c * 128 + t];
        a_s[t] = fmaxf(s, 0.f);
    }
    __syncthreads();
    if (t < 100) {
        float s = S2b[t];
        for (int c = 0; c < 128; ++c) s += a_s[c] * S2w[c * 100 + t];
        b_s[t] = s;  // no activation before hidden layer
    }
    __syncthreads();
    if (t < 100) {
        float s = Hb[t];
        for (int c = 0; c < 100; ++c) s += b_s[c] * Hw[c * 100 + t];
        c_s[t] = fmaxf(s, 0.f);
    }
    __syncthreads();
    if (t == 0) {
        float s = Ob[0];
        for (int c = 0; c < 100; ++c) s += c_s[c] * Ow[c];
        out[0] = s;
    }
}

extern "C" void kernel_launch(void* const* d_in, const int* in_sizes, int n_in,
                              void* d_out, int out_size, void* d_ws, size_t ws_size,
                              hipStream_t stream) {
    const float* h0   = (const float*)d_in[0];
    const float* edge = (const float*)d_in[1];
    const int*   nbr  = (const int*)d_in[2];
    const float* Vw = (const float*)d_in[3];
    const float* Vb = (const float*)d_in[4];
    const float* Ew = (const float*)d_in[5];
    const float* Eb = (const float*)d_in[6];
    const float* Uw = (const float*)d_in[7];
    const float* Ub = (const float*)d_in[8];
    const float* Rw = (const float*)d_in[9];
    const float* Rb = (const float*)d_in[10];
    const float* S1w = (const float*)d_in[11];
    const float* S1b = (const float*)d_in[12];
    const float* S2w = (const float*)d_in[13];
    const float* S2b = (const float*)d_in[14];
    const float* Hw = (const float*)d_in[15];
    const float* Hb = (const float*)d_in[16];
    const float* Ow = (const float*)d_in[17];
    const float* Ob = (const float*)d_in[18];
    float* out = (float*)d_out;

    // workspace layout (~112.1 MB)
    char* ws = (char*)d_ws;
    float* hA    = (float*)(ws);                 // 200000*70 floats = 56 MB
    float* hB    = (float*)(ws + 56000000);      // 56 MB
    float* Bstep = (float*)(ws + 112000000);     // 146*70
    float* btot  = Bstep + 10220;                // 70 (+2 pad)
    float* Rc    = btot + 72;                    // 70*128
    float* fm    = Rc + 8960;                    // 128
    unsigned short* Btg = (unsigned short*)(fm + 128);  // 80*160 bf16 = 25600 B
    float* bias80 = (float*)(Btg + 80 * 160);           // 80 floats

    prep_kernel<<<1, 256, 0, stream>>>(Vw, Vb, Ew, Eb, Uw, Ub, Rw, Bstep, btot, Rc,
                                       Btg, bias80);
    hipMemsetAsync(fm, 0, 128 * sizeof(float), stream);

    const int nblk = NNODES / 64;  // 3125
    const float* cur = h0;
    for (int s = 0; s < 48; ++s) {
        float* o = (s & 1) ? hB : hA;
        step_kernel<<<nblk, 256, 0, stream>>>(cur, edge, nbr, Btg, bias80, o, s & 15);
        cur = o;
    }
    readout_kernel<<<nblk, 256, 0, stream>>>(cur, Rc, Rb, fm);
    mlp_kernel<<<1, 128, 0, stream>>>(fm, S1w, S1b, S2w, S2b, Hw, Hb, Ow, Ob, out);
}

// Round 7
// 1747.343 us; speedup vs baseline: 3.3955x; 1.9830x over previous
//
#include <hip/hip_runtime.h>
#include <hip/hip_bf16.h>

// MPNN, round 6: bf16 h state (stride 72, 16B-aligned rows), zero-LDS-A steps
// with direct global->VGPR MFMA fragments, K padded to 224 with ZERO B-rows in
// the pads (so fragment-tail garbage contributes 0). bf16 MFMA readout.
//
// Folded math (verified rounds 4/5): per step
//   h' = relu([hv | hg | e] @ B + btot),  B rows: U1 ; Vw@U2 ; Ew@U3
//   readout fm = sum_nodes relu(h @ (Rw[:70]+Rw[70:]) + Rb); then tiny MLP.

#define NNODES 200000
#define DEG 16

typedef __attribute__((ext_vector_type(8))) short short8;
typedef __attribute__((ext_vector_type(4))) float f32x4;

__device__ __forceinline__ unsigned short f2bf(float f) {
    unsigned u = __float_as_uint(f);
    unsigned r = 0x7FFFu + ((u >> 16) & 1u);
    return (unsigned short)((u + r) >> 16);
}

// ---------------- prep: fold weights, build bf16 B tables ----------------
__global__ void prep_kernel(const float* __restrict__ Vw, const float* __restrict__ Vb,
                            const float* __restrict__ Ew, const float* __restrict__ Eb,
                            const float* __restrict__ Uw, const float* __restrict__ Ub,
                            const float* __restrict__ Rw,
                            float* __restrict__ Bstep, unsigned short* __restrict__ Btg,
                            float* __restrict__ bias80, unsigned short* __restrict__ Rcg) {
    const int t = threadIdx.x;
    // Bstep[146][70]: [Uw[0:70]; Vw@Uw[70:140]; Ew@Uw[140:146]]
    for (int idx = t; idx < 70 * 70; idx += 256) Bstep[idx] = Uw[idx];
    for (int idx = t; idx < 70 * 70; idx += 256) {
        const int c = idx / 70, n = idx % 70;
        float s = 0.f;
        for (int c2 = 0; c2 < 70; ++c2) s += Vw[c * 70 + c2] * Uw[(70 + c2) * 70 + n];
        Bstep[(70 + c) * 70 + n] = s;
    }
    for (int idx = t; idx < 6 * 70; idx += 256) {
        const int c = idx / 70, n = idx % 70;
        float s = 0.f;
        for (int c2 = 0; c2 < 6; ++c2) s += Ew[c * 6 + c2] * Uw[(140 + c2) * 70 + n];
        Bstep[(140 + c) * 70 + n] = s;
    }
    __syncthreads();
    // Btg[n=80][k=224], transposed, bf16. K map: 0..69 hv, 96..165 hg, 192..197 e, else 0.
    for (int idx = t; idx < 80 * 224; idx += 256) {
        const int n = idx / 224, k = idx % 224;
        float v = 0.f;
        if (n < 70) {
            if (k < 70) v = Bstep[k * 70 + n];
            else if (k >= 96 && k < 166) v = Bstep[(k - 26) * 70 + n];    // rows 70..139
            else if (k >= 192 && k < 198) v = Bstep[(k - 52) * 70 + n];   // rows 140..145
        }
        Btg[idx] = f2bf(v);
    }
    // fused bias
    for (int n = t; n < 80; n += 256) {
        float s = 0.f;
        if (n < 70) {
            s = Ub[n];
            for (int c2 = 0; c2 < 70; ++c2) s += Vb[c2] * Uw[(70 + c2) * 70 + n];
            for (int c2 = 0; c2 < 6; ++c2) s += Eb[c2] * Uw[(140 + c2) * 70 + n];
        }
        bias80[n] = s;
    }
    // Rcg[n=128][k=96] bf16, rows 70..95 zero
    for (int idx = t; idx < 128 * 96; idx += 256) {
        const int n = idx / 96, k = idx % 96;
        const float v = (k < 70) ? (Rw[k * 128 + n] + Rw[(70 + k) * 128 + n]) : 0.f;
        Rcg[idx] = f2bf(v);
    }
}

// ---------------- input conversions (once per launch) ----------------
__global__ void conv_h_kernel(const float* __restrict__ h0, unsigned short* __restrict__ hb) {
    const long total = (long)NNODES * 36;  // 36 uints per 72-elem row
    for (long i = (long)blockIdx.x * blockDim.x + threadIdx.x; i < total;
         i += (long)gridDim.x * blockDim.x) {
        const long node = i / 36;
        const int kp = (int)(i % 36);
        unsigned v = 0u;
        if (kp < 35) {
            const float* p = h0 + node * 70 + kp * 2;
            v = (unsigned)f2bf(p[0]) | ((unsigned)f2bf(p[1]) << 16);
        }
        ((unsigned*)(hb + node * 72))[kp] = v;
    }
}

__global__ void conv_e_kernel(const float* __restrict__ e, unsigned short* __restrict__ eb) {
    const long total = (long)NNODES * DEG * 4;  // 4 uints per 8-elem row
    for (long i = (long)blockIdx.x * blockDim.x + threadIdx.x; i < total;
         i += (long)gridDim.x * blockDim.x) {
        const long row = i / 4;
        const int c = (int)(i % 4);
        unsigned v = 0u;
        if (c < 3) {
            const float* p = e + row * 6 + c * 2;
            v = (unsigned)f2bf(p[0]) | ((unsigned)f2bf(p[1]) << 16);
        }
        ((unsigned*)(eb + row * 8))[c] = v;
    }
}

// ---------------- one message-passing step ----------------
// 512 thr = 8 waves, 128 nodes/block. A-fragments straight from global bf16.
__global__ __launch_bounds__(512) void step_kernel(
    const unsigned short* __restrict__ hin, const unsigned short* __restrict__ edgeb,
    const int* __restrict__ nbr, const unsigned short* __restrict__ Btg,
    const float* __restrict__ bias80, unsigned short* __restrict__ hout, const int j) {
    __shared__ __align__(16) unsigned short Btb[80 * 232];  // stride 232: 2-way banks only
    __shared__ float bias_s[80];
    const int tid = threadIdx.x;
    const long node0 = (long)blockIdx.x * 128;

    for (int i = tid; i < 80 * 112; i += 512) {  // 224 bf16 = 112 uints per row
        const int n = i / 112, kp = i % 112;
        *(unsigned int*)&Btb[n * 232 + kp * 2] = ((const unsigned int*)Btg)[i];
    }
    if (tid < 80) bias_s[tid] = bias80[tid];

    const int w = tid >> 6, l = tid & 63;
    const int lm = l & 15, lhi = l >> 4, lk = lhi * 8;
    const long anode = node0 + w * 16 + lm;
    const long nl = anode < NNODES ? anode : (NNODES - 1);
    const int g = nbr[nl * DEG + j];

    short8 a[7];
    {
        const unsigned short* hr = hin + nl * 72;
        a[0] = *(const short8*)(hr + lk);
        a[1] = *(const short8*)(hr + 32 + lk);
        a[2] = *(const short8*)(hr + 64 + lk);   // cols 64..69 + pad garbage (B rows 0)
        const unsigned short* gr = hin + (long)g * 72;
        a[3] = *(const short8*)(gr + lk);
        a[4] = *(const short8*)(gr + 32 + lk);
        a[5] = *(const short8*)(gr + 64 + lk);
        a[6] = *(const short8*)(edgeb + (nl * DEG + j) * 8 + lk);  // e0..5 + garbage
    }
    __syncthreads();

    f32x4 acc[5] = {{0.f, 0.f, 0.f, 0.f}, {0.f, 0.f, 0.f, 0.f}, {0.f, 0.f, 0.f, 0.f},
                    {0.f, 0.f, 0.f, 0.f}, {0.f, 0.f, 0.f, 0.f}};
#pragma unroll
    for (int kt = 0; kt < 7; ++kt) {
#pragma unroll
        for (int nt = 0; nt < 5; ++nt) {
            const short8 b = *(const short8*)&Btb[(nt * 16 + lm) * 232 + kt * 32 + lk];
            acc[nt] = __builtin_amdgcn_mfma_f32_16x16x32_bf16(a[kt], b, acc[nt], 0, 0, 0);
        }
    }

    // D: col = lane&15, row = (lane>>4)*4 + r (verified)
#pragma unroll
    for (int nt = 0; nt < 5; ++nt) {
        const int col = nt * 16 + lm;
        if (col < 70) {
            const float bias = bias_s[col];
#pragma unroll
            for (int r = 0; r < 4; ++r) {
                const long dnode = node0 + w * 16 + lhi * 4 + r;
                if (dnode < NNODES)
                    hout[dnode * 72 + col] = f2bf(fmaxf(acc[nt][r] + bias, 0.f));
            }
        }
    }
}

// ---------------- readout: fm[128] += sum relu(h @ Rc + Rb), MFMA bf16 ----------------
__global__ __launch_bounds__(512) void readout_kernel(
    const unsigned short* __restrict__ hb, const unsigned short* __restrict__ Rcg,
    const float* __restrict__ Rb, float* __restrict__ fm) {
    __shared__ __align__(16) unsigned short Rs[128 * 104];  // stride 104: 2-way banks
    __shared__ float Rb_s[128];
    __shared__ float red[8][128];
    const int tid = threadIdx.x;
    const long node0 = (long)blockIdx.x * 128;

    for (int i = tid; i < 128 * 48; i += 512) {  // 96 bf16 = 48 uints per row
        const int n = i / 48, kp = i % 48;
        *(unsigned int*)&Rs[n * 104 + kp * 2] = ((const unsigned int*)Rcg)[i];
    }
    if (tid < 128) Rb_s[tid] = Rb[tid];

    const int w = tid >> 6, l = tid & 63;
    const int lm = l & 15, lhi = l >> 4, lk = lhi * 8;
    const long anode = node0 + w * 16 + lm;
    const long nl = anode < NNODES ? anode : (NNODES - 1);
    short8 a[3];
    {
        const unsigned short* hr = hb + nl * 72;
        a[0] = *(const short8*)(hr + lk);
        a[1] = *(const short8*)(hr + 32 + lk);
        a[2] = *(const short8*)(hr + 64 + lk);
    }
    __syncthreads();

    f32x4 acc[8] = {{0.f, 0.f, 0.f, 0.f}, {0.f, 0.f, 0.f, 0.f}, {0.f, 0.f, 0.f, 0.f},
                    {0.f, 0.f, 0.f, 0.f}, {0.f, 0.f, 0.f, 0.f}, {0.f, 0.f, 0.f, 0.f},
                    {0.f, 0.f, 0.f, 0.f}, {0.f, 0.f, 0.f, 0.f}};
#pragma unroll
    for (int kt = 0; kt < 3; ++kt) {
#pragma unroll
        for (int nt = 0; nt < 8; ++nt) {
            const short8 b = *(const short8*)&Rs[(nt * 16 + lm) * 104 + kt * 32 + lk];
            acc[nt] = __builtin_amdgcn_mfma_f32_16x16x32_bf16(a[kt], b, acc[nt], 0, 0, 0);
        }
    }
#pragma unroll
    for (int nt = 0; nt < 8; ++nt) {
        const int col = nt * 16 + lm;
        const float bias = Rb_s[col];
        float s = 0.f;
#pragma unroll
        for (int r = 0; r < 4; ++r) {
            const long dnode = node0 + w * 16 + lhi * 4 + r;
            if (dnode < NNODES) s += fmaxf(acc[nt][r] + bias, 0.f);
        }
        s += __shfl_xor(s, 16);
        s += __shfl_xor(s, 32);
        if (l < 16) red[w][col] = s;
    }
    __syncthreads();
    if (tid < 128) {
        float s = 0.f;
#pragma unroll
        for (int r = 0; r < 8; ++r) s += red[r][tid];
        atomicAdd(&fm[tid], s);
    }
}

// ---------------- tiny MLP tail (fp32, unchanged) ----------------
__global__ void mlp_kernel(const float* __restrict__ fm,
                           const float* __restrict__ S1w, const float* __restrict__ S1b,
                           const float* __restrict__ S2w, const float* __restrict__ S2b,
                           const float* __restrict__ Hw, const float* __restrict__ Hb,
                           const float* __restrict__ Ow, const float* __restrict__ Ob,
                           float* __restrict__ out) {
    __shared__ float fms[128], a_s[128], b_s[100], c_s[100];
    const int t = threadIdx.x;
    fms[t] = fm[t];
    __syncthreads();
    {
        float s = S1b[t];
        for (int c = 0; c < 128; ++c) s += fms[c] * S1w[c * 128 + t];
        a_s[t] = fmaxf(s, 0.f);
    }
    __syncthreads();
    if (t < 100) {
        float s = S2b[t];
        for (int c = 0; c < 128; ++c) s += a_s[c] * S2w[c * 100 + t];
        b_s[t] = s;  // no activation before hidden layer
    }
    __syncthreads();
    if (t < 100) {
        float s = Hb[t];
        for (int c = 0; c < 100; ++c) s += b_s[c] * Hw[c * 100 + t];
        c_s[t] = fmaxf(s, 0.f);
    }
    __syncthreads();
    if (t == 0) {
        float s = Ob[0];
        for (int c = 0; c < 100; ++c) s += c_s[c] * Ow[c];
        out[0] = s;
    }
}

extern "C" void kernel_launch(void* const* d_in, const int* in_sizes, int n_in,
                              void* d_out, int out_size, void* d_ws, size_t ws_size,
                              hipStream_t stream) {
    const float* h0   = (const float*)d_in[0];
    const float* edge = (const float*)d_in[1];
    const int*   nbr  = (const int*)d_in[2];
    const float* Vw = (const float*)d_in[3];
    const float* Vb = (const float*)d_in[4];
    const float* Ew = (const float*)d_in[5];
    const float* Eb = (const float*)d_in[6];
    const float* Uw = (const float*)d_in[7];
    const float* Ub = (const float*)d_in[8];
    const float* Rw = (const float*)d_in[9];
    const float* Rb = (const float*)d_in[10];
    const float* S1w = (const float*)d_in[11];
    const float* S1b = (const float*)d_in[12];
    const float* S2w = (const float*)d_in[13];
    const float* S2b = (const float*)d_in[14];
    const float* Hw = (const float*)d_in[15];
    const float* Hb = (const float*)d_in[16];
    const float* Ow = (const float*)d_in[17];
    const float* Ob = (const float*)d_in[18];
    float* out = (float*)d_out;

    // workspace layout (~108.9 MB, all offsets 16B-aligned)
    char* ws = (char*)d_ws;
    unsigned short* hA    = (unsigned short*)(ws);              // 200000*72 bf16 + pad
    unsigned short* hB    = (unsigned short*)(ws + 28801024);   // same
    unsigned short* edgeb = (unsigned short*)(ws + 57602048);   // 200000*16*8 bf16 + pad
    unsigned short* Btg   = (unsigned short*)(ws + 108803072);  // 80*224 bf16
    unsigned short* Rcg   = (unsigned short*)(ws + 108838912);  // 128*96 bf16
    float* bias80 = (float*)(ws + 108863488);                   // 80
    float* fm     = (float*)(ws + 108863808);                   // 128
    float* Bstep  = (float*)(ws + 108864320);                   // 146*70 fp32 scratch

    conv_h_kernel<<<2048, 256, 0, stream>>>(h0, hA);
    conv_e_kernel<<<2048, 256, 0, stream>>>(edge, edgeb);
    prep_kernel<<<1, 256, 0, stream>>>(Vw, Vb, Ew, Eb, Uw, Ub, Rw,
                                       Bstep, Btg, bias80, Rcg);
    hipMemsetAsync(fm, 0, 128 * sizeof(float), stream);

    const int nblk = (NNODES + 127) / 128;  // 1563
    const unsigned short* cur = hA;
    for (int s = 0; s < 48; ++s) {
        unsigned short* o = (s & 1) ? hA : hB;  // s=0 writes hB; s=47 writes hA
        step_kernel<<<nblk, 512, 0, stream>>>(cur, edgeb, nbr, Btg, bias80, o, s & 15);
        cur = o;
    }
    readout_kernel<<<nblk, 512, 0, stream>>>(cur, Rcg, Rb, fm);
    mlp_kernel<<<1, 128, 0, stream>>>(fm, S1w, S1b, S2w, S2b, Hw, Hb, Ow, Ob, out);
}

// Round 8
// 1664.555 us; speedup vs baseline: 3.5644x; 1.0497x over previous
//
#include <hip/hip_runtime.h>
#include <hip/hip_bf16.h>

// MPNN, round 8: bf16 h state (stride 72), direct global->VGPR A fragments,
// fragment-ordered B blobs (1KB per MFMA fragment) for conflict-free flat LDS
// staging/reads. Parallelized prep (was 100us single-block).
//
// Folded math (verified r4-r7): per step
//   h' = relu([hv | hg | e] @ B + btot),  B rows: U1 ; Vw@U2 ; Ew@U3
//   readout fm = sum_nodes relu(h @ (Rw[:70]+Rw[70:]) + Rb); then tiny MLP.
// K padded to 224 (0-pad B rows kill fragment-tail garbage), N padded to 80.

#define NNODES 200000
#define DEG 16

typedef __attribute__((ext_vector_type(8))) short short8;
typedef __attribute__((ext_vector_type(4))) float f32x4;

__device__ __forceinline__ unsigned short f2bf(float f) {
    unsigned u = __float_as_uint(f);
    unsigned r = 0x7FFFu + ((u >> 16) & 1u);
    return (unsigned short)((u + r) >> 16);
}

// map padded k (0..223) -> Bstep row (0..145) or -1
__device__ __forceinline__ int kmap(int k) {
    if (k < 70) return k;                       // hv
    if (k >= 96 && k < 166) return k - 26;      // hg -> rows 70..139
    if (k >= 192 && k < 198) return k - 52;     // e  -> rows 140..145
    return -1;
}

// ---------------- prepA: folds + bias + readout fragments (96 blocks) ----------------
__global__ void prepA_kernel(const float* __restrict__ Vw, const float* __restrict__ Vb,
                             const float* __restrict__ Ew, const float* __restrict__ Eb,
                             const float* __restrict__ Uw, const float* __restrict__ Ub,
                             const float* __restrict__ Rw,
                             float* __restrict__ Bstep, float* __restrict__ bias80,
                             unsigned short* __restrict__ Rcg) {
    const int b = blockIdx.x, t = threadIdx.x;
    if (b < 70) {
        if (t < 70) {
            // U1 copy
            Bstep[b * 70 + t] = Uw[b * 70 + t];
            // W2 = Vw @ Uw[70:140], row b
            float s = 0.f;
            for (int c2 = 0; c2 < 70; ++c2) s += Vw[b * 70 + c2] * Uw[(70 + c2) * 70 + t];
            Bstep[(70 + b) * 70 + t] = s;
        }
    } else if (b == 70) {
        // We = Ew @ Uw[140:146]
        for (int i = t; i < 6 * 70; i += 256) {
            const int c = i / 70, n = i % 70;
            float s = 0.f;
            for (int c2 = 0; c2 < 6; ++c2) s += Ew[c * 6 + c2] * Uw[(140 + c2) * 70 + n];
            Bstep[(140 + c) * 70 + n] = s;
        }
    } else if (b == 71) {
        // fused bias
        if (t < 80) {
            float s = 0.f;
            if (t < 70) {
                s = Ub[t];
                for (int c2 = 0; c2 < 70; ++c2) s += Vb[c2] * Uw[(70 + c2) * 70 + t];
                for (int c2 = 0; c2 < 6; ++c2) s += Eb[c2] * Uw[(140 + c2) * 70 + t];
            }
            bias80[t] = s;
        }
    } else {
        // readout fragments: f = kt*8+nt, 24 frags of 512 bf16
        const int f = b - 72;
        const int nt = f & 7, kt = f >> 3;
        for (int e = t; e < 512; e += 256) {
            const int l = e >> 3, j = e & 7;
            const int col = nt * 16 + (l & 15);
            const int k = kt * 32 + (l >> 4) * 8 + j;
            const float v = (k < 70) ? (Rw[k * 128 + col] + Rw[(70 + k) * 128 + col]) : 0.f;
            Rcg[f * 512 + e] = f2bf(v);
        }
    }
}

// ---------------- prepB: step-B fragments (35 blocks) ----------------
__global__ void prepB_kernel(const float* __restrict__ Bstep, unsigned short* __restrict__ Btg) {
    const int f = blockIdx.x, t = threadIdx.x;   // f = kt*5 + nt
    const int nt = f % 5, kt = f / 5;
    for (int e = t; e < 512; e += 256) {
        const int l = e >> 3, j = e & 7;
        const int col = nt * 16 + (l & 15);
        const int k = kt * 32 + (l >> 4) * 8 + j;
        const int kr = kmap(k);
        const float v = (col < 70 && kr >= 0) ? Bstep[kr * 70 + col] : 0.f;
        Btg[f * 512 + e] = f2bf(v);
    }
}

// ---------------- input conversions ----------------
__global__ void conv_h_kernel(const float* __restrict__ h0, unsigned short* __restrict__ hb) {
    const long total = (long)NNODES * 36;  // 36 uints per 72-elem row
    for (long i = (long)blockIdx.x * blockDim.x + threadIdx.x; i < total;
         i += (long)gridDim.x * blockDim.x) {
        const long node = i / 36;
        const int kp = (int)(i % 36);
        unsigned v = 0u;
        if (kp < 35) {
            const float* p = h0 + node * 70 + kp * 2;
            v = (unsigned)f2bf(p[0]) | ((unsigned)f2bf(p[1]) << 16);
        }
        ((unsigned*)(hb + node * 72))[kp] = v;
    }
}

__global__ void conv_e_kernel(const float* __restrict__ e, unsigned short* __restrict__ eb) {
    const long total = (long)NNODES * DEG * 4;  // 4 uints per 8-elem row
    for (long i = (long)blockIdx.x * blockDim.x + threadIdx.x; i < total;
         i += (long)gridDim.x * blockDim.x) {
        const long row = i / 4;
        const int c = (int)(i % 4);
        unsigned v = 0u;
        if (c < 3) {
            const float* p = e + row * 6 + c * 2;
            v = (unsigned)f2bf(p[0]) | ((unsigned)f2bf(p[1]) << 16);
        }
        ((unsigned*)(eb + row * 8))[c] = v;
    }
}

// ---------------- one message-passing step ----------------
// 512 thr = 8 waves, 128 nodes/block. A from global; B flat-fragment LDS.
__global__ __launch_bounds__(512, 4) void step_kernel(
    const unsigned short* __restrict__ hin, const unsigned short* __restrict__ edgeb,
    const int* __restrict__ nbr, const unsigned short* __restrict__ Btg,
    const float* __restrict__ bias80, unsigned short* __restrict__ hout, const int j) {
    __shared__ __align__(16) unsigned short Btb[35 * 512];  // 35 frags x 1KB = 35840 B
    __shared__ float bias_s[80];
    const int tid = threadIdx.x;
    const long node0 = (long)blockIdx.x * 128;

    {   // flat conflict-free staging: 2240 uint4
        const uint4* src = (const uint4*)Btg;
        uint4* dst = (uint4*)Btb;
        for (int i = tid; i < 2240; i += 512) dst[i] = src[i];
    }
    if (tid < 80) bias_s[tid] = bias80[tid];

    const int w = tid >> 6, l = tid & 63;
    const int lm = l & 15, lhi = l >> 4, lk = lhi * 8;
    const int lofs = l * 8;
    const long anode = node0 + w * 16 + lm;
    const long nl = anode < NNODES ? anode : (NNODES - 1);
    const int g = nbr[nl * DEG + j];

    short8 a[7];
    {
        const unsigned short* hr = hin + nl * 72;
        a[0] = *(const short8*)(hr + lk);
        a[1] = *(const short8*)(hr + 32 + lk);
        a[2] = *(const short8*)(hr + 64 + lk);   // tail overlaps next row: B rows zero
        const unsigned short* gr = hin + (long)g * 72;
        a[3] = *(const short8*)(gr + lk);
        a[4] = *(const short8*)(gr + 32 + lk);
        a[5] = *(const short8*)(gr + 64 + lk);
        a[6] = *(const short8*)(edgeb + (nl * DEG + j) * 8 + lk);  // e0..5 + zero-B tail
    }
    __syncthreads();

    f32x4 acc[5] = {{0.f, 0.f, 0.f, 0.f}, {0.f, 0.f, 0.f, 0.f}, {0.f, 0.f, 0.f, 0.f},
                    {0.f, 0.f, 0.f, 0.f}, {0.f, 0.f, 0.f, 0.f}};
#pragma unroll
    for (int kt = 0; kt < 7; ++kt) {
#pragma unroll
        for (int nt = 0; nt < 5; ++nt) {
            const short8 b = *(const short8*)&Btb[(kt * 5 + nt) * 512 + lofs];
            acc[nt] = __builtin_amdgcn_mfma_f32_16x16x32_bf16(a[kt], b, acc[nt], 0, 0, 0);
        }
    }

    // D: col = lane&15, row = (lane>>4)*4 + r (verified)
#pragma unroll
    for (int nt = 0; nt < 5; ++nt) {
        const int col = nt * 16 + lm;
        if (col < 70) {
            const float bias = bias_s[col];
#pragma unroll
            for (int r = 0; r < 4; ++r) {
                const long dnode = node0 + w * 16 + lhi * 4 + r;
                if (dnode < NNODES)
                    hout[dnode * 72 + col] = f2bf(fmaxf(acc[nt][r] + bias, 0.f));
            }
        }
    }
}

// ---------------- readout: fm[128] += sum relu(h @ Rc + Rb) ----------------
__global__ __launch_bounds__(512, 4) void readout_kernel(
    const unsigned short* __restrict__ hb, const unsigned short* __restrict__ Rcg,
    const float* __restrict__ Rb, float* __restrict__ fm) {
    __shared__ __align__(16) unsigned short Rs[24 * 512];  // 24 frags x 1KB
    __shared__ float Rb_s[128];
    __shared__ float red[8][128];
    const int tid = threadIdx.x;
    const long node0 = (long)blockIdx.x * 128;

    {
        const uint4* src = (const uint4*)Rcg;
        uint4* dst = (uint4*)Rs;
        for (int i = tid; i < 1536; i += 512) dst[i] = src[i];
    }
    if (tid < 128) Rb_s[tid] = Rb[tid];

    const int w = tid >> 6, l = tid & 63;
    const int lm = l & 15, lhi = l >> 4, lk = lhi * 8;
    const int lofs = l * 8;
    const long anode = node0 + w * 16 + lm;
    const long nl = anode < NNODES ? anode : (NNODES - 1);
    short8 a[3];
    {
        const unsigned short* hr = hb + nl * 72;
        a[0] = *(const short8*)(hr + lk);
        a[1] = *(const short8*)(hr + 32 + lk);
        a[2] = *(const short8*)(hr + 64 + lk);
    }
    __syncthreads();

    f32x4 acc[8] = {{0.f, 0.f, 0.f, 0.f}, {0.f, 0.f, 0.f, 0.f}, {0.f, 0.f, 0.f, 0.f},
                    {0.f, 0.f, 0.f, 0.f}, {0.f, 0.f, 0.f, 0.f}, {0.f, 0.f, 0.f, 0.f},
                    {0.f, 0.f, 0.f, 0.f}, {0.f, 0.f, 0.f, 0.f}};
#pragma unroll
    for (int kt = 0; kt < 3; ++kt) {
#pragma unroll
        for (int nt = 0; nt < 8; ++nt) {
            const short8 b = *(const short8*)&Rs[(kt * 8 + nt) * 512 + lofs];
            acc[nt] = __builtin_amdgcn_mfma_f32_16x16x32_bf16(a[kt], b, acc[nt], 0, 0, 0);
        }
    }
#pragma unroll
    for (int nt = 0; nt < 8; ++nt) {
        const int col = nt * 16 + lm;
        const float bias = Rb_s[col];
        float s = 0.f;
#pragma unroll
        for (int r = 0; r < 4; ++r) {
            const long dnode = node0 + w * 16 + lhi * 4 + r;
            if (dnode < NNODES) s += fmaxf(acc[nt][r] + bias, 0.f);
        }
        s += __shfl_xor(s, 16);
        s += __shfl_xor(s, 32);
        if (l < 16) red[w][col] = s;
    }
    __syncthreads();
    if (tid < 128) {
        float s = 0.f;
#pragma unroll
        for (int r = 0; r < 8; ++r) s += red[r][tid];
        atomicAdd(&fm[tid], s);
    }
}

// ---------------- tiny MLP tail ----------------
__global__ void mlp_kernel(const float* __restrict__ fm,
                           const float* __restrict__ S1w, const float* __restrict__ S1b,
                           const float* __restrict__ S2w, const float* __restrict__ S2b,
                           const float* __restrict__ Hw, const float* __restrict__ Hb,
                           const float* __restrict__ Ow, const float* __restrict__ Ob,
                           float* __restrict__ out) {
    __shared__ float fms[128], a_s[128], b_s[100], c_s[100];
    const int t = threadIdx.x;
    fms[t] = fm[t];
    __syncthreads();
    {
        float s = S1b[t];
        for (int c = 0; c < 128; ++c) s += fms[c] * S1w[c * 128 + t];
        a_s[t] = fmaxf(s, 0.f);
    }
    __syncthreads();
    if (t < 100) {
        float s = S2b[t];
        for (int c = 0; c < 128; ++c) s += a_s[c] * S2w[c * 100 + t];
        b_s[t] = s;  // no activation before hidden layer
    }
    __syncthreads();
    if (t < 100) {
        float s = Hb[t];
        for (int c = 0; c < 100; ++c) s += b_s[c] * Hw[c * 100 + t];
        c_s[t] = fmaxf(s, 0.f);
    }
    __syncthreads();
    if (t == 0) {
        float s = Ob[0];
        for (int c = 0; c < 100; ++c) s += c_s[c] * Ow[c];
        out[0] = s;
    }
}

extern "C" void kernel_launch(void* const* d_in, const int* in_sizes, int n_in,
                              void* d_out, int out_size, void* d_ws, size_t ws_size,
                              hipStream_t stream) {
    const float* h0   = (const float*)d_in[0];
    const float* edge = (const float*)d_in[1];
    const int*   nbr  = (const int*)d_in[2];
    const float* Vw = (const float*)d_in[3];
    const float* Vb = (const float*)d_in[4];
    const float* Ew = (const float*)d_in[5];
    const float* Eb = (const float*)d_in[6];
    const float* Uw = (const float*)d_in[7];
    const float* Ub = (const float*)d_in[8];
    const float* Rw = (const float*)d_in[9];
    const float* Rb = (const float*)d_in[10];
    const float* S1w = (const float*)d_in[11];
    const float* S1b = (const float*)d_in[12];
    const float* S2w = (const float*)d_in[13];
    const float* S2b = (const float*)d_in[14];
    const float* Hw = (const float*)d_in[15];
    const float* Hb = (const float*)d_in[16];
    const float* Ow = (const float*)d_in[17];
    const float* Ob = (const float*)d_in[18];
    float* out = (float*)d_out;

    // workspace layout (~108.9 MB, all offsets 16B-aligned)
    char* ws = (char*)d_ws;
    unsigned short* hA    = (unsigned short*)(ws);              // 200000*72 bf16 + pad
    unsigned short* hB    = (unsigned short*)(ws + 28801024);   // same
    unsigned short* edgeb = (unsigned short*)(ws + 57602048);   // 200000*16*8 bf16 + pad
    unsigned short* Btg   = (unsigned short*)(ws + 108803072);  // 35*512 bf16 frag blob
    unsigned short* Rcg   = (unsigned short*)(ws + 108838912);  // 24*512 bf16 frag blob
    float* bias80 = (float*)(ws + 108863488);                   // 80
    float* fm     = (float*)(ws + 108863808);                   // 128
    float* Bstep  = (float*)(ws + 108864320);                   // 146*70 fp32 scratch

    conv_h_kernel<<<2048, 256, 0, stream>>>(h0, hA);
    conv_e_kernel<<<2048, 256, 0, stream>>>(edge, edgeb);
    prepA_kernel<<<96, 256, 0, stream>>>(Vw, Vb, Ew, Eb, Uw, Ub, Rw, Bstep, bias80, Rcg);
    prepB_kernel<<<35, 256, 0, stream>>>(Bstep, Btg);
    hipMemsetAsync(fm, 0, 128 * sizeof(float), stream);

    const int nblk = (NNODES + 127) / 128;  // 1563
    const unsigned short* cur = hA;
    for (int s = 0; s < 48; ++s) {
        unsigned short* o = (s & 1) ? hA : hB;  // s=0 writes hB; s=47 writes hA
        step_kernel<<<nblk, 512, 0, stream>>>(cur, edgeb, nbr, Btg, bias80, o, s & 15);
        cur = o;
    }
    readout_kernel<<<nblk, 512, 0, stream>>>(cur, Rcg, Rb, fm);
    mlp_kernel<<<1, 128, 0, stream>>>(fm, S1w, S1b, S2w, S2b, Hw, Hb, Ow, Ob, out);
}